// Round 5
// baseline (760.379 us; speedup 1.0000x reference)
//
#include <hip/hip_runtime.h>
#include <cstdint>
#include <cstddef>

// BiARMA: N=50000, E=800000, IN=64, HID=64, OUT=32, K=2 stacks, T=2 layers.
//  - gcn_norm factored into dinv pre/post scaling
//  - Agg(xW) = Agg(x)W: propagate width-64; stacks packed/merged
//  - CSR built on-device; atomic-free gathers fused into consuming GEMMs
//  - latency hiding: 5 blocks/CU (32KB LDS, launch_bounds), unroll-2 gather chains
//  - feature broadcast straight from float4 via compile-time v_readlane

#define NN 50000
#define EE 800000
#define NCHUNK ((NN + 255) / 256)  // 196

__device__ __forceinline__ float rl(float v, int l) {
  return __int_as_float(__builtin_amdgcn_readlane(__float_as_int(v), l));
}

// feature c (compile-time) from float4-per-16-lane row layout
__device__ __forceinline__ float bcast(const float4& a, int c) {
  int sl = c >> 2;
  switch (c & 3) {
    case 0: return rl(a.x, sl);
    case 1: return rl(a.y, sl);
    case 2: return rl(a.z, sl);
    default: return rl(a.w, sl);
  }
}

__device__ __forceinline__ void red4(float4& a) {
#pragma unroll
  for (int off = 16; off < 64; off <<= 1) {
    a.x += __shfl_xor(a.x, off);
    a.y += __shfl_xor(a.y, off);
    a.z += __shfl_xor(a.z, off);
    a.w += __shfl_xor(a.w, off);
  }
}

__device__ __forceinline__ void acc4(float4& a, const float4& v) {
  a.x += v.x; a.y += v.y; a.z += v.z; a.w += v.w;
}

// ---------------- CSR build ----------------

__global__ __launch_bounds__(256) void k_degree(const int* __restrict__ dst,
                                                int* __restrict__ deg) {
  int i = blockIdx.x * 256 + threadIdx.x;
  if (i < EE) atomicAdd(&deg[dst[i]], 1);
}

__global__ __launch_bounds__(256) void k_part(const int* __restrict__ deg,
                                              int* __restrict__ partial) {
  int i = blockIdx.x * 256 + threadIdx.x;
  int v = (i < NN) ? deg[i] : 0;
#pragma unroll
  for (int off = 1; off < 64; off <<= 1) v += __shfl_xor(v, off);
  __shared__ int wsum[4];
  if ((threadIdx.x & 63) == 0) wsum[threadIdx.x >> 6] = v;
  __syncthreads();
  if (threadIdx.x == 0) partial[blockIdx.x] = wsum[0] + wsum[1] + wsum[2] + wsum[3];
}

__global__ __launch_bounds__(256) void k_scanp(const int* __restrict__ partial,
                                               int* __restrict__ chunkbase) {
  __shared__ int sc[256];
  int t = threadIdx.x;
  int v = (t < NCHUNK) ? partial[t] : 0;
  sc[t] = v;
  __syncthreads();
  for (int off = 1; off < 256; off <<= 1) {
    int u = (t >= off) ? sc[t - off] : 0;
    __syncthreads();
    sc[t] += u;
    __syncthreads();
  }
  if (t < NCHUNK) chunkbase[t] = sc[t] - v;  // exclusive
}

__global__ __launch_bounds__(256) void k_rows(const int* __restrict__ deg,
                                              const int* __restrict__ chunkbase,
                                              int* __restrict__ rowstart,
                                              float* __restrict__ dinv,
                                              int* __restrict__ cursor) {
  __shared__ int sc[256];
  int t = threadIdx.x;
  int i = blockIdx.x * 256 + t;
  int d = (i < NN) ? deg[i] : 0;
  sc[t] = d;
  __syncthreads();
  for (int off = 1; off < 256; off <<= 1) {
    int u = (t >= off) ? sc[t - off] : 0;
    __syncthreads();
    sc[t] += u;
    __syncthreads();
  }
  if (i < NN) {
    rowstart[i] = chunkbase[blockIdx.x] + sc[t] - d;
    dinv[i] = (d > 0) ? rsqrtf((float)d) : 0.f;
    cursor[i] = 0;
  }
  if (blockIdx.x == 0 && t == 0) rowstart[NN] = EE;
}

__global__ __launch_bounds__(256) void k_fill(const int* __restrict__ src,
                                              const int* __restrict__ dst,
                                              const int* __restrict__ rowstart,
                                              int* __restrict__ cursor,
                                              int* __restrict__ csr) {
  int i = blockIdx.x * 256 + threadIdx.x;
  if (i < EE) {
    int d = dst[i];
    int pos = rowstart[d] + atomicAdd(&cursor[d], 1);
    csr[pos] = src[i];
  }
}

// ---------------- agg(x*dinv[s]) * dinv[n] -> aggxs [N,64] ----------------

__global__ __launch_bounds__(256, 6) void k_aggx(const float* __restrict__ x,
                                                 const float* __restrict__ dinv,
                                                 const int* __restrict__ rowstart,
                                                 const int* __restrict__ csr,
                                                 float* __restrict__ outp) {
  int lane = threadIdx.x & 63;
  int f4 = lane & 15, es = lane >> 4;
  int wid = (blockIdx.x * 256 + threadIdx.x) >> 6;
  int nw = (gridDim.x * 256) >> 6;
  const float4* x4 = (const float4*)x;
  for (int n = wid; n < NN; n += nw) {
    int beg = rowstart[n], end = rowstart[n + 1];
    float4 a = {0.f, 0.f, 0.f, 0.f}, b = {0.f, 0.f, 0.f, 0.f};
    int j = beg + es;
    for (; j + 4 < end; j += 8) {
      int s0 = csr[j], s1 = csr[j + 4];
      float d0 = dinv[s0], d1 = dinv[s1];
      float4 v0 = x4[(size_t)s0 * 16 + f4];
      float4 v1 = x4[(size_t)s1 * 16 + f4];
      a.x = fmaf(v0.x, d0, a.x); a.y = fmaf(v0.y, d0, a.y);
      a.z = fmaf(v0.z, d0, a.z); a.w = fmaf(v0.w, d0, a.w);
      b.x = fmaf(v1.x, d1, b.x); b.y = fmaf(v1.y, d1, b.y);
      b.z = fmaf(v1.z, d1, b.z); b.w = fmaf(v1.w, d1, b.w);
    }
    if (j < end) {
      int s = csr[j];
      float d = dinv[s];
      float4 v = x4[(size_t)s * 16 + f4];
      a.x = fmaf(v.x, d, a.x); a.y = fmaf(v.y, d, a.y);
      a.z = fmaf(v.z, d, a.z); a.w = fmaf(v.w, d, a.w);
    }
    acc4(a, b);
    red4(a);
    if (lane < 16) {
      float dn = dinv[n];
      a.x *= dn; a.y *= dn; a.z *= dn; a.w *= dn;
      ((float4*)outp)[(size_t)n * 16 + f4] = a;
    }
  }
}

// ---------------- ARMA1 t=0, both stacks (coalesced, compute-bound) ----------------

__global__ __launch_bounds__(256) void k_t0(const float* __restrict__ x,
                                            const float* __restrict__ aggxs,
                                            const float* __restrict__ initW,
                                            const float* __restrict__ rootW,
                                            const float* __restrict__ bias,
                                            const float* __restrict__ dinv,
                                            float* __restrict__ root01,
                                            float* __restrict__ s01) {
  __shared__ float Wi[8192];
  __shared__ float Wr[8192];
  for (int i = threadIdx.x; i < 8192; i += 256) { Wi[i] = initW[i]; Wr[i] = rootW[i]; }
  __syncthreads();
  int lane = threadIdx.x & 63;
  float b_0 = bias[lane], b_1 = bias[64 + lane];
  int wid = (blockIdx.x * 256 + threadIdx.x) >> 6;
  int nw = (gridDim.x * 256) >> 6;
  for (int n = wid; n < NN; n += nw) {
    float dn = dinv[n];
    float xv = x[(size_t)n * 64 + lane];
    float gv = aggxs[(size_t)n * 64 + lane];
    float r0 = b_0, r1 = b_1;
    float i0 = 0.f, i1 = 0.f;
#pragma unroll
    for (int c = 0; c < 64; c++) {
      float xc = rl(xv, c), gc = rl(gv, c);
      r0 = fmaf(xc, Wr[c * 64 + lane], r0);
      r1 = fmaf(xc, Wr[4096 + c * 64 + lane], r1);
      i0 = fmaf(gc, Wi[c * 64 + lane], i0);
      i1 = fmaf(gc, Wi[4096 + c * 64 + lane], i1);
    }
    size_t b = (size_t)n * 128 + lane;
    root01[b] = r0;
    root01[b + 64] = r1;
    s01[b] = fmaxf(i0 + r0, 0.f) * dn;
    s01[b + 64] = fmaxf(i1 + r1, 0.f) * dn;
  }
}

// ---------------- ARMA1 t=1 fused: gather s0,s1 + GEMM + h ----------------

__global__ __launch_bounds__(256, 5) void k_t1(const float* __restrict__ s01,
                                               const float* __restrict__ root01,
                                               const float* __restrict__ W,
                                               const float* __restrict__ dinv,
                                               const int* __restrict__ rowstart,
                                               const int* __restrict__ csr,
                                               float* __restrict__ h,
                                               float* __restrict__ hs) {
  __shared__ float Ws[8192];
  for (int i = threadIdx.x; i < 8192; i += 256) Ws[i] = W[i];
  __syncthreads();
  int lane = threadIdx.x & 63;
  int f4 = lane & 15, es = lane >> 4;
  int wid = (blockIdx.x * 256 + threadIdx.x) >> 6;
  int nw = (gridDim.x * 256) >> 6;
  const float4* in4 = (const float4*)s01;
  for (int n = wid; n < NN; n += nw) {
    int beg = rowstart[n], end = rowstart[n + 1];
    float4 a0 = {0.f, 0.f, 0.f, 0.f}, a1 = {0.f, 0.f, 0.f, 0.f};
    int j = beg + es;
    for (; j + 4 < end; j += 8) {
      int s0 = csr[j], s1 = csr[j + 4];
      const float4* r0 = in4 + (size_t)s0 * 32;
      const float4* r1 = in4 + (size_t)s1 * 32;
      float4 v00 = r0[f4], v01 = r0[16 + f4];
      float4 v10 = r1[f4], v11 = r1[16 + f4];
      acc4(a0, v00); acc4(a1, v01);
      acc4(a0, v10); acc4(a1, v11);
    }
    if (j < end) {
      int s = csr[j];
      const float4* r = in4 + (size_t)s * 32;
      float4 v0 = r[f4], v1 = r[16 + f4];
      acc4(a0, v0); acc4(a1, v1);
    }
    red4(a0);
    red4(a1);
    float dn = dinv[n];
    float c0 = 0.f, c1 = 0.f;
#pragma unroll
    for (int c = 0; c < 64; c++) {
      c0 = fmaf(bcast(a0, c), Ws[c * 64 + lane], c0);
      c1 = fmaf(bcast(a1, c), Ws[4096 + c * 64 + lane], c1);
    }
    size_t b = (size_t)n * 128 + lane;
    float o0 = fmaxf(fmaf(dn, c0, root01[b]), 0.f);
    float o1 = fmaxf(fmaf(dn, c1, root01[b + 64]), 0.f);
    float hv = 0.5f * (o0 + o1);
    h[(size_t)n * 64 + lane] = hv;
    hs[(size_t)n * 64 + lane] = hv * dn;
  }
}

// ---------------- ARMA2 t=0 fused: gather hs + GEMM (stacks packed) ----------------

__global__ __launch_bounds__(256, 5) void k2_t0(const float* __restrict__ h,
                                                const float* __restrict__ hs,
                                                const float* __restrict__ initW2,
                                                const float* __restrict__ rootW2,
                                                const float* __restrict__ b2,
                                                const float* __restrict__ dinv,
                                                const int* __restrict__ rowstart,
                                                const int* __restrict__ csr,
                                                float* __restrict__ root2,
                                                float* __restrict__ s2) {
  __shared__ float Wi[4096];
  __shared__ float Wr[4096];
  for (int i = threadIdx.x; i < 4096; i += 256) { Wi[i] = initW2[i]; Wr[i] = rootW2[i]; }
  __syncthreads();
  int lane = threadIdx.x & 63;
  int f4 = lane & 15, es = lane >> 4;
  int k = lane >> 5, col = lane & 31;
  float bv = b2[lane];
  int wid = (blockIdx.x * 256 + threadIdx.x) >> 6;
  int nw = (gridDim.x * 256) >> 6;
  const float4* in4 = (const float4*)hs;
  for (int n = wid; n < NN; n += nw) {
    int beg = rowstart[n], end = rowstart[n + 1];
    float4 a = {0.f, 0.f, 0.f, 0.f}, b = {0.f, 0.f, 0.f, 0.f};
    int j = beg + es;
    for (; j + 4 < end; j += 8) {
      int s0 = csr[j], s1 = csr[j + 4];
      float4 v0 = in4[(size_t)s0 * 16 + f4];
      float4 v1 = in4[(size_t)s1 * 16 + f4];
      acc4(a, v0); acc4(b, v1);
    }
    if (j < end) {
      int s = csr[j];
      acc4(a, in4[(size_t)s * 16 + f4]);
    }
    acc4(a, b);
    red4(a);
    float dn = dinv[n];
    float hv = h[(size_t)n * 64 + lane];
    float accR = bv;
    float accI = 0.f;
#pragma unroll
    for (int c = 0; c < 64; c++) {
      float xc = rl(hv, c);
      float gc = bcast(a, c);
      accR = fmaf(xc, Wr[k * 2048 + c * 32 + col], accR);
      accI = fmaf(gc, Wi[k * 2048 + c * 32 + col], accI);
    }
    float o = fmaxf(fmaf(dn, accI, accR), 0.f);
    root2[(size_t)n * 64 + lane] = accR;
    s2[(size_t)n * 64 + lane] = o * dn;
  }
}

// ---------------- ARMA2 t=1 fused: gather s2 + GEMM + mean -> out ----------------

__global__ __launch_bounds__(256, 6) void k2_t1(const float* __restrict__ s2,
                                                const float* __restrict__ root2,
                                                const float* __restrict__ W2,
                                                const float* __restrict__ dinv,
                                                const int* __restrict__ rowstart,
                                                const int* __restrict__ csr,
                                                float* __restrict__ outp) {
  __shared__ float Ws[2048];
  for (int i = threadIdx.x; i < 2048; i += 256) Ws[i] = W2[i];
  __syncthreads();
  int lane = threadIdx.x & 63;
  int f4 = lane & 15, es = lane >> 4;
  int k = lane >> 5, col = lane & 31;
  int wid = (blockIdx.x * 256 + threadIdx.x) >> 6;
  int nw = (gridDim.x * 256) >> 6;
  const float4* in4 = (const float4*)s2;
  for (int n = wid; n < NN; n += nw) {
    int beg = rowstart[n], end = rowstart[n + 1];
    float4 a = {0.f, 0.f, 0.f, 0.f}, b = {0.f, 0.f, 0.f, 0.f};
    int j = beg + es;
    for (; j + 4 < end; j += 8) {
      int s0 = csr[j], s1 = csr[j + 4];
      float4 v0 = in4[(size_t)s0 * 16 + f4];
      float4 v1 = in4[(size_t)s1 * 16 + f4];
      acc4(a, v0); acc4(b, v1);
    }
    if (j < end) {
      int s = csr[j];
      acc4(a, in4[(size_t)s * 16 + f4]);
    }
    acc4(a, b);
    red4(a);
    float dn = dinv[n];
    float acc = 0.f;
#pragma unroll
    for (int c = 0; c < 32; c++) {
      float p0 = bcast(a, c);
      float p1 = bcast(a, 32 + c);
      float pc = (lane < 32) ? p0 : p1;
      acc = fmaf(pc, Ws[k * 1024 + c * 32 + col], acc);
    }
    float o = fmaxf(fmaf(dn, acc, root2[(size_t)n * 64 + lane]), 0.f);
    o += __shfl_xor(o, 32);
    if (lane < 32) outp[(size_t)n * 32 + col] = 0.5f * o;
  }
}

// ---------------- host launch ----------------

extern "C" void kernel_launch(void* const* d_in, const int* in_sizes, int n_in,
                              void* d_out, int out_size, void* d_ws, size_t ws_size,
                              hipStream_t stream) {
  const float* x = (const float*)d_in[0];
  const int* edge_index = (const int*)d_in[1];
  const float* initW1 = (const float*)d_in[2];
  const float* w1 = (const float*)d_in[3];
  const float* rootW1 = (const float*)d_in[4];
  const float* b1 = (const float*)d_in[5];
  const float* initW2 = (const float*)d_in[6];
  const float* w2 = (const float*)d_in[7];
  const float* rootW2 = (const float*)d_in[8];
  const float* b2 = (const float*)d_in[9];
  float* out = (float*)d_out;

  const int* src = edge_index;
  const int* dst = edge_index + EE;

  size_t off = 0;
  auto carve = [&](size_t bytes) {
    size_t r = off;
    off = (off + bytes + 255) & ~(size_t)255;
    return r;
  };
  char* ws = (char*)d_ws;
  int* deg = (int*)(ws + carve((size_t)NN * 4));
  int* rowstart = (int*)(ws + carve((size_t)(NN + 1) * 4));
  int* csr = (int*)(ws + carve((size_t)EE * 4));
  float* dinv = (float*)(ws + carve((size_t)NN * 4));
  int* cursor = (int*)(ws + carve((size_t)NN * 4));
  int* partial = (int*)(ws + carve(256 * 4));
  int* chunkbase = (int*)(ws + carve(256 * 4));
  float* B1 = (float*)(ws + carve((size_t)NN * 64 * 4));   // aggxs, later h
  float* B2 = (float*)(ws + carve((size_t)NN * 128 * 4));  // root01, later root2
  float* B3 = (float*)(ws + carve((size_t)NN * 128 * 4));  // s01, later s2
  float* B4 = (float*)(ws + carve((size_t)NN * 64 * 4));   // hs
  (void)ws_size; (void)in_sizes; (void)n_in; (void)out_size;

  const int EB = (EE + 255) / 256;

  hipMemsetAsync(deg, 0, (size_t)NN * 4, stream);
  k_degree<<<EB, 256, 0, stream>>>(dst, deg);
  k_part<<<NCHUNK, 256, 0, stream>>>(deg, partial);
  k_scanp<<<1, 256, 0, stream>>>(partial, chunkbase);
  k_rows<<<NCHUNK, 256, 0, stream>>>(deg, chunkbase, rowstart, dinv, cursor);
  k_fill<<<EB, 256, 0, stream>>>(src, dst, rowstart, cursor, csr);

  k_aggx<<<1536, 256, 0, stream>>>(x, dinv, rowstart, csr, B1);
  k_t0<<<512, 256, 0, stream>>>(x, B1, initW1, rootW1, b1, dinv, B2, B3);
  k_t1<<<1280, 256, 0, stream>>>(B3, B2, w1, dinv, rowstart, csr, B1, B4);
  k2_t0<<<1280, 256, 0, stream>>>(B1, B4, initW2, rootW2, b2, dinv, rowstart, csr, B2, B3);
  k2_t1<<<1536, 256, 0, stream>>>(B3, B2, w2, dinv, rowstart, csr, out);
}

// Round 6
// 469.416 us; speedup vs baseline: 1.6198x; 1.6198x over previous
//
#include <hip/hip_runtime.h>
#include <cstdint>
#include <cstddef>

// BiARMA: N=50000, E=800000, IN=64, HID=64, OUT=32, K=2 stacks, T=2 layers.
//  - gcn_norm factored into dinv pre/post scaling
//  - Agg(xW) = Agg(x)W: propagate width-64; stacks packed/merged
//  - CSR built on-device; atomic-free gathers fused into consuming GEMMs
//  - unroll-2 gather chains for MLP; grids sized to the LDS block/CU limit
//  - NO min-waves launch_bounds: round-5 showed (256,5) crushes VGPR 84->48 -> spills
//    (WRITE_SIZE 25->114MB, FETCH 189->576MB, k_t1 115->274us). Allocator must be free.

#define NN 50000
#define EE 800000
#define NCHUNK ((NN + 255) / 256)  // 196

__device__ __forceinline__ float rl(float v, int l) {
  return __int_as_float(__builtin_amdgcn_readlane(__float_as_int(v), l));
}

// feature c (compile-time) from float4-per-16-lane row layout
__device__ __forceinline__ float bcast(const float4& a, int c) {
  int sl = c >> 2;
  switch (c & 3) {
    case 0: return rl(a.x, sl);
    case 1: return rl(a.y, sl);
    case 2: return rl(a.z, sl);
    default: return rl(a.w, sl);
  }
}

__device__ __forceinline__ void red4(float4& a) {
#pragma unroll
  for (int off = 16; off < 64; off <<= 1) {
    a.x += __shfl_xor(a.x, off);
    a.y += __shfl_xor(a.y, off);
    a.z += __shfl_xor(a.z, off);
    a.w += __shfl_xor(a.w, off);
  }
}

__device__ __forceinline__ void acc4(float4& a, const float4& v) {
  a.x += v.x; a.y += v.y; a.z += v.z; a.w += v.w;
}

// ---------------- CSR build ----------------

__global__ __launch_bounds__(256) void k_degree(const int* __restrict__ dst,
                                                int* __restrict__ deg) {
  int i = blockIdx.x * 256 + threadIdx.x;
  if (i < EE) atomicAdd(&deg[dst[i]], 1);
}

__global__ __launch_bounds__(256) void k_part(const int* __restrict__ deg,
                                              int* __restrict__ partial) {
  int i = blockIdx.x * 256 + threadIdx.x;
  int v = (i < NN) ? deg[i] : 0;
#pragma unroll
  for (int off = 1; off < 64; off <<= 1) v += __shfl_xor(v, off);
  __shared__ int wsum[4];
  if ((threadIdx.x & 63) == 0) wsum[threadIdx.x >> 6] = v;
  __syncthreads();
  if (threadIdx.x == 0) partial[blockIdx.x] = wsum[0] + wsum[1] + wsum[2] + wsum[3];
}

__global__ __launch_bounds__(256) void k_scanp(const int* __restrict__ partial,
                                               int* __restrict__ chunkbase) {
  __shared__ int sc[256];
  int t = threadIdx.x;
  int v = (t < NCHUNK) ? partial[t] : 0;
  sc[t] = v;
  __syncthreads();
  for (int off = 1; off < 256; off <<= 1) {
    int u = (t >= off) ? sc[t - off] : 0;
    __syncthreads();
    sc[t] += u;
    __syncthreads();
  }
  if (t < NCHUNK) chunkbase[t] = sc[t] - v;  // exclusive
}

__global__ __launch_bounds__(256) void k_rows(const int* __restrict__ deg,
                                              const int* __restrict__ chunkbase,
                                              int* __restrict__ rowstart,
                                              float* __restrict__ dinv,
                                              int* __restrict__ cursor) {
  __shared__ int sc[256];
  int t = threadIdx.x;
  int i = blockIdx.x * 256 + t;
  int d = (i < NN) ? deg[i] : 0;
  sc[t] = d;
  __syncthreads();
  for (int off = 1; off < 256; off <<= 1) {
    int u = (t >= off) ? sc[t - off] : 0;
    __syncthreads();
    sc[t] += u;
    __syncthreads();
  }
  if (i < NN) {
    rowstart[i] = chunkbase[blockIdx.x] + sc[t] - d;
    dinv[i] = (d > 0) ? rsqrtf((float)d) : 0.f;
    cursor[i] = 0;
  }
  if (blockIdx.x == 0 && t == 0) rowstart[NN] = EE;
}

__global__ __launch_bounds__(256) void k_fill(const int* __restrict__ src,
                                              const int* __restrict__ dst,
                                              const int* __restrict__ rowstart,
                                              int* __restrict__ cursor,
                                              int* __restrict__ csr) {
  int i = blockIdx.x * 256 + threadIdx.x;
  if (i < EE) {
    int d = dst[i];
    int pos = rowstart[d] + atomicAdd(&cursor[d], 1);
    csr[pos] = src[i];
  }
}

// ---------------- agg(x*dinv[s]) * dinv[n] -> aggxs [N,64] ----------------

__global__ __launch_bounds__(256) void k_aggx(const float* __restrict__ x,
                                              const float* __restrict__ dinv,
                                              const int* __restrict__ rowstart,
                                              const int* __restrict__ csr,
                                              float* __restrict__ outp) {
  int lane = threadIdx.x & 63;
  int f4 = lane & 15, es = lane >> 4;
  int wid = (blockIdx.x * 256 + threadIdx.x) >> 6;
  int nw = (gridDim.x * 256) >> 6;
  const float4* x4 = (const float4*)x;
  for (int n = wid; n < NN; n += nw) {
    int beg = rowstart[n], end = rowstart[n + 1];
    float4 a = {0.f, 0.f, 0.f, 0.f}, b = {0.f, 0.f, 0.f, 0.f};
    int j = beg + es;
    for (; j + 4 < end; j += 8) {
      int s0 = csr[j], s1 = csr[j + 4];
      float d0 = dinv[s0], d1 = dinv[s1];
      float4 v0 = x4[(size_t)s0 * 16 + f4];
      float4 v1 = x4[(size_t)s1 * 16 + f4];
      a.x = fmaf(v0.x, d0, a.x); a.y = fmaf(v0.y, d0, a.y);
      a.z = fmaf(v0.z, d0, a.z); a.w = fmaf(v0.w, d0, a.w);
      b.x = fmaf(v1.x, d1, b.x); b.y = fmaf(v1.y, d1, b.y);
      b.z = fmaf(v1.z, d1, b.z); b.w = fmaf(v1.w, d1, b.w);
    }
    if (j < end) {
      int s = csr[j];
      float d = dinv[s];
      float4 v = x4[(size_t)s * 16 + f4];
      a.x = fmaf(v.x, d, a.x); a.y = fmaf(v.y, d, a.y);
      a.z = fmaf(v.z, d, a.z); a.w = fmaf(v.w, d, a.w);
    }
    acc4(a, b);
    red4(a);
    if (lane < 16) {
      float dn = dinv[n];
      a.x *= dn; a.y *= dn; a.z *= dn; a.w *= dn;
      ((float4*)outp)[(size_t)n * 16 + f4] = a;
    }
  }
}

// ---------------- ARMA1 t=0, both stacks (coalesced, compute-bound) ----------------

__global__ __launch_bounds__(256) void k_t0(const float* __restrict__ x,
                                            const float* __restrict__ aggxs,
                                            const float* __restrict__ initW,
                                            const float* __restrict__ rootW,
                                            const float* __restrict__ bias,
                                            const float* __restrict__ dinv,
                                            float* __restrict__ root01,
                                            float* __restrict__ s01) {
  __shared__ float Wi[8192];
  __shared__ float Wr[8192];
  for (int i = threadIdx.x; i < 8192; i += 256) { Wi[i] = initW[i]; Wr[i] = rootW[i]; }
  __syncthreads();
  int lane = threadIdx.x & 63;
  float b_0 = bias[lane], b_1 = bias[64 + lane];
  int wid = (blockIdx.x * 256 + threadIdx.x) >> 6;
  int nw = (gridDim.x * 256) >> 6;
  for (int n = wid; n < NN; n += nw) {
    float dn = dinv[n];
    float xv = x[(size_t)n * 64 + lane];
    float gv = aggxs[(size_t)n * 64 + lane];
    float r0 = b_0, r1 = b_1;
    float i0 = 0.f, i1 = 0.f;
#pragma unroll
    for (int c = 0; c < 64; c++) {
      float xc = rl(xv, c), gc = rl(gv, c);
      r0 = fmaf(xc, Wr[c * 64 + lane], r0);
      r1 = fmaf(xc, Wr[4096 + c * 64 + lane], r1);
      i0 = fmaf(gc, Wi[c * 64 + lane], i0);
      i1 = fmaf(gc, Wi[4096 + c * 64 + lane], i1);
    }
    size_t b = (size_t)n * 128 + lane;
    root01[b] = r0;
    root01[b + 64] = r1;
    s01[b] = fmaxf(i0 + r0, 0.f) * dn;
    s01[b + 64] = fmaxf(i1 + r1, 0.f) * dn;
  }
}

// ---------------- ARMA1 t=1 fused: gather s0,s1 + GEMM + h ----------------

__global__ __launch_bounds__(256) void k_t1(const float* __restrict__ s01,
                                            const float* __restrict__ root01,
                                            const float* __restrict__ W,
                                            const float* __restrict__ dinv,
                                            const int* __restrict__ rowstart,
                                            const int* __restrict__ csr,
                                            float* __restrict__ h,
                                            float* __restrict__ hs) {
  __shared__ float Ws[8192];
  for (int i = threadIdx.x; i < 8192; i += 256) Ws[i] = W[i];
  __syncthreads();
  int lane = threadIdx.x & 63;
  int f4 = lane & 15, es = lane >> 4;
  int wid = (blockIdx.x * 256 + threadIdx.x) >> 6;
  int nw = (gridDim.x * 256) >> 6;
  const float4* in4 = (const float4*)s01;
  for (int n = wid; n < NN; n += nw) {
    int beg = rowstart[n], end = rowstart[n + 1];
    float4 a0 = {0.f, 0.f, 0.f, 0.f}, a1 = {0.f, 0.f, 0.f, 0.f};
    int j = beg + es;
    for (; j + 4 < end; j += 8) {
      int s0 = csr[j], s1 = csr[j + 4];
      const float4* r0 = in4 + (size_t)s0 * 32;
      const float4* r1 = in4 + (size_t)s1 * 32;
      float4 v00 = r0[f4], v01 = r0[16 + f4];
      float4 v10 = r1[f4], v11 = r1[16 + f4];
      acc4(a0, v00); acc4(a1, v01);
      acc4(a0, v10); acc4(a1, v11);
    }
    if (j < end) {
      int s = csr[j];
      const float4* r = in4 + (size_t)s * 32;
      float4 v0 = r[f4], v1 = r[16 + f4];
      acc4(a0, v0); acc4(a1, v1);
    }
    red4(a0);
    red4(a1);
    float dn = dinv[n];
    float c0 = 0.f, c1 = 0.f;
#pragma unroll
    for (int c = 0; c < 64; c++) {
      c0 = fmaf(bcast(a0, c), Ws[c * 64 + lane], c0);
      c1 = fmaf(bcast(a1, c), Ws[4096 + c * 64 + lane], c1);
    }
    size_t b = (size_t)n * 128 + lane;
    float o0 = fmaxf(fmaf(dn, c0, root01[b]), 0.f);
    float o1 = fmaxf(fmaf(dn, c1, root01[b + 64]), 0.f);
    float hv = 0.5f * (o0 + o1);
    h[(size_t)n * 64 + lane] = hv;
    hs[(size_t)n * 64 + lane] = hv * dn;
  }
}

// ---------------- ARMA2 t=0 fused: gather hs + GEMM (stacks packed) ----------------

__global__ __launch_bounds__(256) void k2_t0(const float* __restrict__ h,
                                             const float* __restrict__ hs,
                                             const float* __restrict__ initW2,
                                             const float* __restrict__ rootW2,
                                             const float* __restrict__ b2,
                                             const float* __restrict__ dinv,
                                             const int* __restrict__ rowstart,
                                             const int* __restrict__ csr,
                                             float* __restrict__ root2,
                                             float* __restrict__ s2) {
  __shared__ float Wi[4096];
  __shared__ float Wr[4096];
  for (int i = threadIdx.x; i < 4096; i += 256) { Wi[i] = initW2[i]; Wr[i] = rootW2[i]; }
  __syncthreads();
  int lane = threadIdx.x & 63;
  int f4 = lane & 15, es = lane >> 4;
  int k = lane >> 5, col = lane & 31;
  float bv = b2[lane];
  int wid = (blockIdx.x * 256 + threadIdx.x) >> 6;
  int nw = (gridDim.x * 256) >> 6;
  const float4* in4 = (const float4*)hs;
  for (int n = wid; n < NN; n += nw) {
    int beg = rowstart[n], end = rowstart[n + 1];
    float4 a = {0.f, 0.f, 0.f, 0.f}, b = {0.f, 0.f, 0.f, 0.f};
    int j = beg + es;
    for (; j + 4 < end; j += 8) {
      int s0 = csr[j], s1 = csr[j + 4];
      float4 v0 = in4[(size_t)s0 * 16 + f4];
      float4 v1 = in4[(size_t)s1 * 16 + f4];
      acc4(a, v0); acc4(b, v1);
    }
    if (j < end) {
      int s = csr[j];
      acc4(a, in4[(size_t)s * 16 + f4]);
    }
    acc4(a, b);
    red4(a);
    float dn = dinv[n];
    float hv = h[(size_t)n * 64 + lane];
    float accR = bv;
    float accI = 0.f;
#pragma unroll
    for (int c = 0; c < 64; c++) {
      float xc = rl(hv, c);
      float gc = bcast(a, c);
      accR = fmaf(xc, Wr[k * 2048 + c * 32 + col], accR);
      accI = fmaf(gc, Wi[k * 2048 + c * 32 + col], accI);
    }
    float o = fmaxf(fmaf(dn, accI, accR), 0.f);
    root2[(size_t)n * 64 + lane] = accR;
    s2[(size_t)n * 64 + lane] = o * dn;
  }
}

// ---------------- ARMA2 t=1 fused: gather s2 + GEMM + mean -> out ----------------

__global__ __launch_bounds__(256) void k2_t1(const float* __restrict__ s2,
                                             const float* __restrict__ root2,
                                             const float* __restrict__ W2,
                                             const float* __restrict__ dinv,
                                             const int* __restrict__ rowstart,
                                             const int* __restrict__ csr,
                                             float* __restrict__ outp) {
  __shared__ float Ws[2048];
  for (int i = threadIdx.x; i < 2048; i += 256) Ws[i] = W2[i];
  __syncthreads();
  int lane = threadIdx.x & 63;
  int f4 = lane & 15, es = lane >> 4;
  int k = lane >> 5, col = lane & 31;
  int wid = (blockIdx.x * 256 + threadIdx.x) >> 6;
  int nw = (gridDim.x * 256) >> 6;
  const float4* in4 = (const float4*)s2;
  for (int n = wid; n < NN; n += nw) {
    int beg = rowstart[n], end = rowstart[n + 1];
    float4 a = {0.f, 0.f, 0.f, 0.f}, b = {0.f, 0.f, 0.f, 0.f};
    int j = beg + es;
    for (; j + 4 < end; j += 8) {
      int s0 = csr[j], s1 = csr[j + 4];
      float4 v0 = in4[(size_t)s0 * 16 + f4];
      float4 v1 = in4[(size_t)s1 * 16 + f4];
      acc4(a, v0); acc4(b, v1);
    }
    if (j < end) {
      int s = csr[j];
      acc4(a, in4[(size_t)s * 16 + f4]);
    }
    acc4(a, b);
    red4(a);
    float dn = dinv[n];
    float acc = 0.f;
#pragma unroll
    for (int c = 0; c < 32; c++) {
      float p0 = bcast(a, c);
      float p1 = bcast(a, 32 + c);
      float pc = (lane < 32) ? p0 : p1;
      acc = fmaf(pc, Ws[k * 1024 + c * 32 + col], acc);
    }
    float o = fmaxf(fmaf(dn, acc, root2[(size_t)n * 64 + lane]), 0.f);
    o += __shfl_xor(o, 32);
    if (lane < 32) outp[(size_t)n * 32 + col] = 0.5f * o;
  }
}

// ---------------- host launch ----------------

extern "C" void kernel_launch(void* const* d_in, const int* in_sizes, int n_in,
                              void* d_out, int out_size, void* d_ws, size_t ws_size,
                              hipStream_t stream) {
  const float* x = (const float*)d_in[0];
  const int* edge_index = (const int*)d_in[1];
  const float* initW1 = (const float*)d_in[2];
  const float* w1 = (const float*)d_in[3];
  const float* rootW1 = (const float*)d_in[4];
  const float* b1 = (const float*)d_in[5];
  const float* initW2 = (const float*)d_in[6];
  const float* w2 = (const float*)d_in[7];
  const float* rootW2 = (const float*)d_in[8];
  const float* b2 = (const float*)d_in[9];
  float* out = (float*)d_out;

  const int* src = edge_index;
  const int* dst = edge_index + EE;

  size_t off = 0;
  auto carve = [&](size_t bytes) {
    size_t r = off;
    off = (off + bytes + 255) & ~(size_t)255;
    return r;
  };
  char* ws = (char*)d_ws;
  int* deg = (int*)(ws + carve((size_t)NN * 4));
  int* rowstart = (int*)(ws + carve((size_t)(NN + 1) * 4));
  int* csr = (int*)(ws + carve((size_t)EE * 4));
  float* dinv = (float*)(ws + carve((size_t)NN * 4));
  int* cursor = (int*)(ws + carve((size_t)NN * 4));
  int* partial = (int*)(ws + carve(256 * 4));
  int* chunkbase = (int*)(ws + carve(256 * 4));
  float* B1 = (float*)(ws + carve((size_t)NN * 64 * 4));   // aggxs, later h
  float* B2 = (float*)(ws + carve((size_t)NN * 128 * 4));  // root01, later root2
  float* B3 = (float*)(ws + carve((size_t)NN * 128 * 4));  // s01, later s2
  float* B4 = (float*)(ws + carve((size_t)NN * 64 * 4));   // hs
  (void)ws_size; (void)in_sizes; (void)n_in; (void)out_size;

  const int EB = (EE + 255) / 256;

  hipMemsetAsync(deg, 0, (size_t)NN * 4, stream);
  k_degree<<<EB, 256, 0, stream>>>(dst, deg);
  k_part<<<NCHUNK, 256, 0, stream>>>(deg, partial);
  k_scanp<<<1, 256, 0, stream>>>(partial, chunkbase);
  k_rows<<<NCHUNK, 256, 0, stream>>>(deg, chunkbase, rowstart, dinv, cursor);
  k_fill<<<EB, 256, 0, stream>>>(src, dst, rowstart, cursor, csr);

  k_aggx<<<1536, 256, 0, stream>>>(x, dinv, rowstart, csr, B1);
  k_t0<<<1024, 256, 0, stream>>>(x, B1, initW1, rootW1, b1, dinv, B2, B3);
  k_t1<<<1280, 256, 0, stream>>>(B3, B2, w1, dinv, rowstart, csr, B1, B4);
  k2_t0<<<1280, 256, 0, stream>>>(B1, B4, initW2, rootW2, b2, dinv, rowstart, csr, B2, B3);
  k2_t1<<<1536, 256, 0, stream>>>(B3, B2, w2, dinv, rowstart, csr, out);
}